// Round 2
// baseline (325.435 us; speedup 1.0000x reference)
//
#include <hip/hip_runtime.h>
#include <hip/hip_bf16.h>

// Problem constants
constexpr int B_ = 2, S_ = 2048, D_ = 1024, H_ = 16, HD_ = 64;

typedef __attribute__((ext_vector_type(8))) short bf16x8;
typedef __attribute__((ext_vector_type(4))) float f32x4;

// ---------------------------------------------------------------------------
// fp32 -> bf16 elementwise convert (vectorized: float4 in, 4x bf16 out)
// ---------------------------------------------------------------------------
__global__ void f32_to_bf16_vec(const float* __restrict__ in,
                                __hip_bfloat16* __restrict__ out, int n) {
    int i = (blockIdx.x * 256 + threadIdx.x) * 4;
    if (i >= n) return;
    float4 v = *reinterpret_cast<const float4*>(in + i);
    union { ushort4 u; __hip_bfloat16 h[4]; } pk;
    pk.h[0] = __float2bfloat16(v.x);
    pk.h[1] = __float2bfloat16(v.y);
    pk.h[2] = __float2bfloat16(v.z);
    pk.h[3] = __float2bfloat16(v.w);
    *reinterpret_cast<ushort4*>(out + i) = pk.u;
}

// ---------------------------------------------------------------------------
// 1024x1024 fp32 -> transposed bf16 (dst[n][k] = src[k][n])
// ---------------------------------------------------------------------------
__global__ void transpose_f32_to_bf16(const float* __restrict__ src,
                                      __hip_bfloat16* __restrict__ dst) {
    __shared__ float tile[32][33];
    const int bx = blockIdx.x * 32;   // src col
    const int by = blockIdx.y * 32;   // src row
    const int c = threadIdx.x & 31;
    const int r0 = threadIdx.x >> 5;  // 0..7
#pragma unroll
    for (int p = 0; p < 4; ++p) {
        int r = r0 + p * 8;
        tile[r][c] = src[(size_t)(by + r) * D_ + bx + c];
    }
    __syncthreads();
#pragma unroll
    for (int p = 0; p < 4; ++p) {
        int r = r0 + p * 8;
        dst[(size_t)(bx + r) * D_ + by + c] = __float2bfloat16(tile[c][r]);
    }
}

// ---------------------------------------------------------------------------
// concat bq|bk|bv -> biasf[3072]
// ---------------------------------------------------------------------------
__global__ void concat_bias(const float* __restrict__ bq, const float* __restrict__ bk,
                            const float* __restrict__ bv, float* __restrict__ dst) {
    int i = blockIdx.x * 256 + threadIdx.x;   // 12 blocks * 256 = 3072
    float v = (i < 1024) ? bq[i] : (i < 2048) ? bk[i - 1024] : bv[i - 2048];
    dst[i] = v;
}

// ---------------------------------------------------------------------------
// bf16 GEMM: C[M][N] = A[M][K] * Bt[N][K]^T + bias[N]
// 128x128 tile, BK=64, 4 waves (2x2), mfma_f32_16x16x32_bf16
// A-frag: row=lane&15, k = 8*(lane>>4)+j (contiguous)   [m92-verified layout]
// C/D:    col=lane&15, row = 4*(lane>>4)+reg            [m89-verified layout]
// ---------------------------------------------------------------------------
template <bool OUT_F32>
__launch_bounds__(256)
__global__ void gemm_bt_kernel(const __hip_bfloat16* __restrict__ A,
                               const __hip_bfloat16* __restrict__ Bt,
                               const float* __restrict__ bias,
                               void* __restrict__ Cout,
                               int M, int N, int K) {
    constexpr int BM = 128, BN = 128, BK = 64, LDP = 72;  // 144B pitch: 16B aligned, 2-way banks
    __shared__ __hip_bfloat16 As[BM][LDP];
    __shared__ __hip_bfloat16 Bs[BN][LDP];

    const int tid = threadIdx.x;
    const int lane = tid & 63;
    const int w = tid >> 6;
    const int wr = w >> 1, wc = w & 1;
    const int g = lane >> 4;       // 0..3
    const int lc = lane & 15;      // 0..15
    const int m0 = blockIdx.x * BM;
    const int n0 = blockIdx.y * BN;

    const int cr = tid >> 3;        // 0..31
    const int cc = (tid & 7) * 8;   // 0..56

    f32x4 acc[4][4] = {};

    for (int k0 = 0; k0 < K; k0 += BK) {
#pragma unroll
        for (int p = 0; p < 4; ++p) {
            int r = cr + 32 * p;
            uint4 va = *reinterpret_cast<const uint4*>(&A[(size_t)(m0 + r) * K + k0 + cc]);
            *reinterpret_cast<uint4*>(&As[r][cc]) = va;
            uint4 vb = *reinterpret_cast<const uint4*>(&Bt[(size_t)(n0 + r) * K + k0 + cc]);
            *reinterpret_cast<uint4*>(&Bs[r][cc]) = vb;
        }
        __syncthreads();
#pragma unroll
        for (int kk = 0; kk < 2; ++kk) {
            bf16x8 af[4], bfr[4];
#pragma unroll
            for (int mi = 0; mi < 4; ++mi)
                af[mi] = *reinterpret_cast<const bf16x8*>(&As[wr * 64 + mi * 16 + lc][kk * 32 + g * 8]);
#pragma unroll
            for (int ni = 0; ni < 4; ++ni)
                bfr[ni] = *reinterpret_cast<const bf16x8*>(&Bs[wc * 64 + ni * 16 + lc][kk * 32 + g * 8]);
#pragma unroll
            for (int mi = 0; mi < 4; ++mi)
#pragma unroll
                for (int ni = 0; ni < 4; ++ni)
                    acc[mi][ni] = __builtin_amdgcn_mfma_f32_16x16x32_bf16(af[mi], bfr[ni], acc[mi][ni], 0, 0, 0);
        }
        __syncthreads();
    }

#pragma unroll
    for (int mi = 0; mi < 4; ++mi)
#pragma unroll
        for (int r = 0; r < 4; ++r) {
            int row = m0 + wr * 64 + mi * 16 + g * 4 + r;
#pragma unroll
            for (int ni = 0; ni < 4; ++ni) {
                int col = n0 + wc * 64 + ni * 16 + lc;
                float v = acc[mi][ni][r] + bias[col];
                if (OUT_F32)
                    ((float*)Cout)[(size_t)row * N + col] = v;
                else
                    ((__hip_bfloat16*)Cout)[(size_t)row * N + col] = __float2bfloat16(v);
            }
        }
}

// ---------------------------------------------------------------------------
// Flash attention with causal mask + ALiBi.
// qkv layout: [(b*S+s)][3072]: cols 0..1023 Q, 1024..2047 K, 2048..3071 V
// (col = h*64 + hd). Block = 4 waves, QBLK=64 (16 q-rows/wave), KVBLK=64.
// ---------------------------------------------------------------------------
__launch_bounds__(256)
__global__ void attn_kernel(const __hip_bfloat16* __restrict__ qkv,
                            __hip_bfloat16* __restrict__ outb) {
    constexpr int LDP = 72;
    __shared__ __hip_bfloat16 Ks[64][LDP];
    __shared__ __hip_bfloat16 Vt[64][LDP];       // transposed: Vt[hd][kpos]
    __shared__ __hip_bfloat16 Ps[4][16][LDP];    // per-wave P tile

    const int tid = threadIdx.x;
    const int lane = tid & 63;
    const int w = tid >> 6;
    const int qt = blockIdx.x;                   // q tile (32)
    const int bh = blockIdx.y;                   // b*H + h (32)
    const int b = bh >> 4, h = bh & 15;
    const int g = lane >> 4;    // 0..3
    const int lc = lane & 15;   // 0..15

    const float slope = exp2f(-0.5f * (float)(h + 1));   // (2^(-8/16))^(h+1)

    const size_t rowstride = 3 * D_;
    const size_t base = (size_t)b * S_ * rowstride + h * HD_;

    // Q fragments for this wave's 16 rows (held in registers)
    const int qrow = qt * 64 + w * 16 + lc;
    bf16x8 aq[2];
#pragma unroll
    for (int kk = 0; kk < 2; ++kk)
        aq[kk] = *reinterpret_cast<const bf16x8*>(&qkv[base + (size_t)qrow * rowstride + kk * 32 + g * 8]);

    f32x4 o[4] = {};
    float m_run[4], l_run[4];
#pragma unroll
    for (int r = 0; r < 4; ++r) { m_run[r] = -3e38f; l_run[r] = 0.f; }

    const int cr = tid >> 3;        // 0..31
    const int cc = (tid & 7) * 8;

    for (int kt = 0; kt <= qt; ++kt) {
        // ---- stage K (direct) and V (transposed) into LDS ----
#pragma unroll
        for (int p = 0; p < 2; ++p) {
            int r = cr + p * 32;
            const size_t grow = base + (size_t)(kt * 64 + r) * rowstride;
            uint4 kv = *reinterpret_cast<const uint4*>(&qkv[grow + D_ + cc]);
            *reinterpret_cast<uint4*>(&Ks[r][cc]) = kv;
            uint4 vv = *reinterpret_cast<const uint4*>(&qkv[grow + 2 * D_ + cc]);
            const __hip_bfloat16* ve = reinterpret_cast<const __hip_bfloat16*>(&vv);
#pragma unroll
            for (int j = 0; j < 8; ++j) Vt[cc + j][r] = ve[j];
        }
        __syncthreads();

        // ---- S = Q K^T ----
        f32x4 s[4] = {};
#pragma unroll
        for (int ni = 0; ni < 4; ++ni)
#pragma unroll
            for (int kk = 0; kk < 2; ++kk) {
                bf16x8 kf = *reinterpret_cast<const bf16x8*>(&Ks[ni * 16 + lc][kk * 32 + g * 8]);
                s[ni] = __builtin_amdgcn_mfma_f32_16x16x32_bf16(aq[kk], kf, s[ni], 0, 0, 0);
            }

        // ---- scale + alibi + mask; online softmax ----
        const bool diag = (kt == qt);
        float pe[4][4];     // [ni][r]
        float mnew[4], rsum[4];
#pragma unroll
        for (int r = 0; r < 4; ++r) {
            const int qg = qt * 64 + w * 16 + g * 4 + r;
            float rm = -3e38f;
#pragma unroll
            for (int ni = 0; ni < 4; ++ni) {
                const int kg = kt * 64 + ni * 16 + lc;
                float v = s[ni][r] * 0.125f + slope * (float)(kg - qg);
                if (diag && kg > qg) v = -3e38f;
                pe[ni][r] = v;
                rm = fmaxf(rm, v);
            }
#pragma unroll
            for (int off = 1; off < 16; off <<= 1)
                rm = fmaxf(rm, __shfl_xor(rm, off, 64));
            mnew[r] = fmaxf(m_run[r], rm);
            float rs = 0.f;
#pragma unroll
            for (int ni = 0; ni < 4; ++ni) {
                float e = __expf(pe[ni][r] - mnew[r]);
                pe[ni][r] = e;
                rs += e;
            }
#pragma unroll
            for (int off = 1; off < 16; off <<= 1)
                rs += __shfl_xor(rs, off, 64);
            rsum[r] = rs;
        }
#pragma unroll
        for (int r = 0; r < 4; ++r) {
            float alpha = __expf(m_run[r] - mnew[r]);
            l_run[r] = l_run[r] * alpha + rsum[r];
            m_run[r] = mnew[r];
#pragma unroll
            for (int oi = 0; oi < 4; ++oi) o[oi][r] *= alpha;
        }

        // ---- P -> LDS (bf16), re-fragment for PV ----
#pragma unroll
        for (int r = 0; r < 4; ++r)
#pragma unroll
            for (int ni = 0; ni < 4; ++ni)
                Ps[w][g * 4 + r][ni * 16 + lc] = __float2bfloat16(pe[ni][r]);

        // ---- O += P V ----
#pragma unroll
        for (int oi = 0; oi < 4; ++oi)
#pragma unroll
            for (int kk = 0; kk < 2; ++kk) {
                bf16x8 pf = *reinterpret_cast<const bf16x8*>(&Ps[w][lc][kk * 32 + g * 8]);
                bf16x8 vf = *reinterpret_cast<const bf16x8*>(&Vt[oi * 16 + lc][kk * 32 + g * 8]);
                o[oi] = __builtin_amdgcn_mfma_f32_16x16x32_bf16(pf, vf, o[oi], 0, 0, 0);
            }
        __syncthreads();
    }

    // ---- epilogue: normalize, write bf16 attn output [(b*S+q)][D] ----
#pragma unroll
    for (int r = 0; r < 4; ++r) {
        float inv = 1.0f / l_run[r];
        const int qg = qt * 64 + w * 16 + g * 4 + r;
#pragma unroll
        for (int oi = 0; oi < 4; ++oi)
            outb[(size_t)(b * S_ + qg) * D_ + h * HD_ + oi * 16 + lc] =
                __float2bfloat16(o[oi][r] * inv);
    }
}

// ---------------------------------------------------------------------------
extern "C" void kernel_launch(void* const* d_in, const int* in_sizes, int n_in,
                              void* d_out, int out_size, void* d_ws, size_t ws_size,
                              hipStream_t stream) {
    const float* x  = (const float*)d_in[0];
    const float* Wq = (const float*)d_in[1];
    const float* bq = (const float*)d_in[2];
    const float* Wk = (const float*)d_in[3];
    const float* bk = (const float*)d_in[4];
    const float* Wv = (const float*)d_in[5];
    const float* bv = (const float*)d_in[6];
    const float* Wo = (const float*)d_in[7];
    const float* bo = (const float*)d_in[8];

    char* ws = (char*)d_ws;
    __hip_bfloat16* xb    = (__hip_bfloat16*)(ws);                       // 8 MB
    __hip_bfloat16* Wqkvt = (__hip_bfloat16*)(ws + (size_t)(8u  << 20)); // 6 MB
    __hip_bfloat16* Wot   = (__hip_bfloat16*)(ws + (size_t)(14u << 20)); // 2 MB
    __hip_bfloat16* qkv   = (__hip_bfloat16*)(ws + (size_t)(16u << 20)); // 24 MB
    __hip_bfloat16* attnb = (__hip_bfloat16*)(ws + (size_t)(40u << 20)); // 8 MB
    float* biasf          = (float*)(ws + (size_t)(48u << 20));          // 12 KB

    const int nX = B_ * S_ * D_;   // 4194304

    f32_to_bf16_vec<<<4096, 256, 0, stream>>>(x, xb, nX);
    transpose_f32_to_bf16<<<dim3(32, 32), 256, 0, stream>>>(Wq, Wqkvt);
    transpose_f32_to_bf16<<<dim3(32, 32), 256, 0, stream>>>(Wk, Wqkvt + D_ * D_);
    transpose_f32_to_bf16<<<dim3(32, 32), 256, 0, stream>>>(Wv, Wqkvt + 2 * D_ * D_);
    transpose_f32_to_bf16<<<dim3(32, 32), 256, 0, stream>>>(Wo, Wot);
    concat_bias<<<12, 256, 0, stream>>>(bq, bk, bv, biasf);

    // QKV projection: [4096 x 1024] @ [1024 x 3072] -> qkv (bf16)
    gemm_bt_kernel<false><<<dim3(32, 24), 256, 0, stream>>>(
        xb, Wqkvt, biasf, qkv, B_ * S_, 3 * D_, D_);

    // Attention
    attn_kernel<<<dim3(S_ / 64, B_ * H_), 256, 0, stream>>>(qkv, attnb);

    // Output projection: [4096 x 1024] @ [1024 x 1024] -> d_out (fp32)
    gemm_bt_kernel<true><<<dim3(32, 8), 256, 0, stream>>>(
        attnb, Wot, bo, (float*)d_out, B_ * S_, D_, D_);
}

// Round 5
// 246.451 us; speedup vs baseline: 1.3205x; 1.3205x over previous
//
#include <hip/hip_runtime.h>
#include <hip/hip_bf16.h>

// Problem constants
constexpr int B_ = 2, S_ = 2048, D_ = 1024, H_ = 16, HD_ = 64;

typedef __attribute__((ext_vector_type(8))) short bf16x8;
typedef __attribute__((ext_vector_type(4))) float f32x4;

// global -> LDS direct copy, 16 B per lane.
// Dest must be linear: wave-uniform base + lane*16 (rule #21 / m104).
typedef __attribute__((address_space(1))) const unsigned char ga_t;
typedef __attribute__((address_space(3))) unsigned char la_t;
__device__ __forceinline__ void gload_lds16(const void* g, void* l) {
    __builtin_amdgcn_global_load_lds((ga_t*)g, (la_t*)l, 16, 0, 0);
}

// ---------------------------------------------------------------------------
// fp32 -> bf16 elementwise convert (float4 in, 4x bf16 out)
// ---------------------------------------------------------------------------
__global__ void f32_to_bf16_vec(const float* __restrict__ in,
                                __hip_bfloat16* __restrict__ out, int n) {
    int i = (blockIdx.x * 256 + threadIdx.x) * 4;
    if (i >= n) return;
    float4 v = *reinterpret_cast<const float4*>(in + i);
    union { ushort4 u; __hip_bfloat16 h[4]; } pk;
    pk.h[0] = __float2bfloat16(v.x);
    pk.h[1] = __float2bfloat16(v.y);
    pk.h[2] = __float2bfloat16(v.z);
    pk.h[3] = __float2bfloat16(v.w);
    *reinterpret_cast<ushort4*>(out + i) = pk.u;
}

// ---------------------------------------------------------------------------
// Fused: 4x (1024x1024 fp32 -> transposed bf16). z selects the matrix.
// ---------------------------------------------------------------------------
__global__ void transpose4_f32_to_bf16(const float* __restrict__ w0,
                                       const float* __restrict__ w1,
                                       const float* __restrict__ w2,
                                       const float* __restrict__ w3,
                                       __hip_bfloat16* __restrict__ d0,
                                       __hip_bfloat16* __restrict__ d1,
                                       __hip_bfloat16* __restrict__ d2,
                                       __hip_bfloat16* __restrict__ d3) {
    __shared__ float tile[32][33];
    const int z = blockIdx.z;
    const float* src = z == 0 ? w0 : z == 1 ? w1 : z == 2 ? w2 : w3;
    __hip_bfloat16* dst = z == 0 ? d0 : z == 1 ? d1 : z == 2 ? d2 : d3;
    const int bx = blockIdx.x * 32;   // src col
    const int by = blockIdx.y * 32;   // src row
    const int c = threadIdx.x & 31;
    const int r0 = threadIdx.x >> 5;  // 0..7
#pragma unroll
    for (int p = 0; p < 4; ++p) {
        int r = r0 + p * 8;
        tile[r][c] = src[(size_t)(by + r) * D_ + bx + c];
    }
    __syncthreads();
#pragma unroll
    for (int p = 0; p < 4; ++p) {
        int r = r0 + p * 8;
        dst[(size_t)(bx + r) * D_ + by + c] = __float2bfloat16(tile[c][r]);
    }
}

// ---------------------------------------------------------------------------
// concat bq|bk|bv -> biasf[3072]
// ---------------------------------------------------------------------------
__global__ void concat_bias(const float* __restrict__ bq, const float* __restrict__ bk,
                            const float* __restrict__ bv, float* __restrict__ dst) {
    int i = blockIdx.x * 256 + threadIdx.x;   // 12 blocks * 256 = 3072
    float v = (i < 1024) ? bq[i] : (i < 2048) ? bk[i - 1024] : bv[i - 2048];
    dst[i] = v;
}

// ---------------------------------------------------------------------------
// bf16 GEMM: C[M][N] = A[M][K] * Bt[N][K]^T + bias[N]
// m97 structure: 128x128 tile, BK=64, global_load_lds w=16, linear LDS +
// XOR-swizzle (col ^= (row&7)<<3 elems) applied via pre-swizzled global
// source and swizzled ds_read (rule #21).
// ---------------------------------------------------------------------------
template <bool OUT_F32>
__launch_bounds__(256)
__global__ void gemm_bt_kernel(const __hip_bfloat16* __restrict__ A,
                               const __hip_bfloat16* __restrict__ Bt,
                               const float* __restrict__ bias,
                               void* __restrict__ Cout,
                               int M, int N, int K) {
    constexpr int BM = 128, BN = 128, BK = 64;
    __shared__ __hip_bfloat16 As[BM][BK];
    __shared__ __hip_bfloat16 Bs[BN][BK];

    const int tid = threadIdx.x;
    const int lane = tid & 63;
    const int w = tid >> 6;
    const int wr = w >> 1, wc = w & 1;
    const int g = lane >> 4;       // 0..3
    const int lc = lane & 15;      // 0..15
    const int m0 = blockIdx.x * BM;
    const int n0 = blockIdx.y * BN;

    // staging: issue p covers rows p*32 + (tid>>3); dest col (tid&7)*8;
    // source col pre-swizzled so LDS[row][c'] = A[row][c' ^ ((row&7)<<3)]
    const int srow = tid >> 3;                      // 0..31  (row&7 == srow&7 for +32p)
    const int sc0 = (tid & 7) * 8;
    const int scol = sc0 ^ ((srow & 7) << 3);

    f32x4 acc[4][4] = {};

    for (int k0 = 0; k0 < K; k0 += BK) {
#pragma unroll
        for (int p = 0; p < 4; ++p) {
            int r = p * 32 + srow;
            gload_lds16(&A[(size_t)(m0 + r) * K + k0 + scol], &As[r][sc0]);
            gload_lds16(&Bt[(size_t)(n0 + r) * K + k0 + scol], &Bs[r][sc0]);
        }
        __syncthreads();
#pragma unroll
        for (int kk = 0; kk < 2; ++kk) {
            bf16x8 af[4], bfr[4];
#pragma unroll
            for (int mi = 0; mi < 4; ++mi) {
                int row = wr * 64 + mi * 16 + lc;
                af[mi] = *reinterpret_cast<const bf16x8*>(
                    &As[row][(kk * 32 + g * 8) ^ ((row & 7) << 3)]);
            }
#pragma unroll
            for (int ni = 0; ni < 4; ++ni) {
                int row = wc * 64 + ni * 16 + lc;
                bfr[ni] = *reinterpret_cast<const bf16x8*>(
                    &Bs[row][(kk * 32 + g * 8) ^ ((row & 7) << 3)]);
            }
#pragma unroll
            for (int mi = 0; mi < 4; ++mi)
#pragma unroll
                for (int ni = 0; ni < 4; ++ni)
                    acc[mi][ni] = __builtin_amdgcn_mfma_f32_16x16x32_bf16(af[mi], bfr[ni], acc[mi][ni], 0, 0, 0);
        }
        __syncthreads();
    }

#pragma unroll
    for (int mi = 0; mi < 4; ++mi)
#pragma unroll
        for (int r = 0; r < 4; ++r) {
            int row = m0 + wr * 64 + mi * 16 + g * 4 + r;
#pragma unroll
            for (int ni = 0; ni < 4; ++ni) {
                int col = n0 + wc * 64 + ni * 16 + lc;
                float v = acc[mi][ni][r] + bias[col];
                if (OUT_F32)
                    ((float*)Cout)[(size_t)row * N + col] = v;
                else
                    ((__hip_bfloat16*)Cout)[(size_t)row * N + col] = __float2bfloat16(v);
            }
        }
}

// ---------------------------------------------------------------------------
// Flash attention, causal + ALiBi.
// Balanced: block pairIdx processes q-tiles (31-pairIdx) then (pairIdx):
// uniform 33 kt-iterations per block.
// K: global_load_lds into linear Ks[64][64], read-swizzled (col ^ (row&7)<<3,
//    source pre-swizzled).
// V: reg-staged transposed into Vt[64][72] with col-XOR swizzle
//    (col ^ ((row>>3)&7)<<3) -> conflict-free scalar writes AND b128 reads.
// ---------------------------------------------------------------------------
__launch_bounds__(256)
__global__ void attn_kernel(const __hip_bfloat16* __restrict__ qkv,
                            __hip_bfloat16* __restrict__ outb) {
    __shared__ __hip_bfloat16 Ks[64][64];
    __shared__ __hip_bfloat16 Vt[64][72];
    __shared__ __hip_bfloat16 Ps[4][16][72];

    const int tid = threadIdx.x;
    const int lane = tid & 63;
    const int w = tid >> 6;
    const int bh = blockIdx.y;                   // b*H + h (32)
    const int b = bh >> 4, h = bh & 15;
    const int g = lane >> 4;    // 0..3
    const int lc = lane & 15;   // 0..15

    const float slope = exp2f(-0.5f * (float)(h + 1));   // (2^(-8/16))^(h+1)

    const size_t rowstride = 3 * D_;
    const size_t base = (size_t)b * S_ * rowstride + h * HD_;

    const int srow = tid >> 3;           // 0..31
    const int sc0 = (tid & 7) * 8;
    const int kscol = sc0 ^ ((srow & 7) << 3);   // K source pre-swizzle
    const int vwsz = (tid & 7) << 3;             // Vt write col-swizzle key

#pragma unroll 1
    for (int phase = 0; phase < 2; ++phase) {
        const int qt = phase == 0 ? (31 - blockIdx.x) : blockIdx.x;

        // Q fragments for this wave's 16 rows
        const int qrow = qt * 64 + w * 16 + lc;
        bf16x8 aq[2];
#pragma unroll
        for (int kk = 0; kk < 2; ++kk)
            aq[kk] = *reinterpret_cast<const bf16x8*>(
                &qkv[base + (size_t)qrow * rowstride + kk * 32 + g * 8]);

        f32x4 o[4] = {};
        float m_run[4], l_run[4];
#pragma unroll
        for (int r = 0; r < 4; ++r) { m_run[r] = -3e38f; l_run[r] = 0.f; }

        for (int kt = 0; kt <= qt; ++kt) {
            // ---- stage K (global_load_lds, linear dest) ----
#pragma unroll
            for (int p = 0; p < 2; ++p) {
                int r = p * 32 + srow;
                gload_lds16(&qkv[base + (size_t)(kt * 64 + r) * rowstride + D_ + kscol],
                            &Ks[r][sc0]);
            }
            // ---- stage V transposed+swizzled (reg-staged) ----
#pragma unroll
            for (int p = 0; p < 2; ++p) {
                int r = p * 32 + srow;
                uint4 vv = *reinterpret_cast<const uint4*>(
                    &qkv[base + (size_t)(kt * 64 + r) * rowstride + 2 * D_ + sc0]);
                const __hip_bfloat16* ve = reinterpret_cast<const __hip_bfloat16*>(&vv);
#pragma unroll
                for (int j = 0; j < 8; ++j)
                    Vt[sc0 + j][r ^ vwsz] = ve[j];   // (row>>3)&7 == tid&7
            }
            __syncthreads();

            // ---- S = Q K^T ----
            f32x4 s[4] = {};
#pragma unroll
            for (int ni = 0; ni < 4; ++ni)
#pragma unroll
                for (int kk = 0; kk < 2; ++kk) {
                    int row = ni * 16 + lc;
                    bf16x8 kf = *reinterpret_cast<const bf16x8*>(
                        &Ks[row][(kk * 32 + g * 8) ^ ((row & 7) << 3)]);
                    s[ni] = __builtin_amdgcn_mfma_f32_16x16x32_bf16(aq[kk], kf, s[ni], 0, 0, 0);
                }

            // ---- scale + alibi + mask; online softmax ----
            const bool diag = (kt == qt);
            float pe[4][4];     // [ni][r]
            float mnew[4], rsum[4];
#pragma unroll
            for (int r = 0; r < 4; ++r) {
                const int qg = qt * 64 + w * 16 + g * 4 + r;
                float rm = -3e38f;
#pragma unroll
                for (int ni = 0; ni < 4; ++ni) {
                    const int kg = kt * 64 + ni * 16 + lc;
                    float v = s[ni][r] * 0.125f + slope * (float)(kg - qg);
                    if (diag && kg > qg) v = -3e38f;
                    pe[ni][r] = v;
                    rm = fmaxf(rm, v);
                }
#pragma unroll
                for (int off = 1; off < 16; off <<= 1)
                    rm = fmaxf(rm, __shfl_xor(rm, off, 64));
                mnew[r] = fmaxf(m_run[r], rm);
                float rs = 0.f;
#pragma unroll
                for (int ni = 0; ni < 4; ++ni) {
                    float e = __expf(pe[ni][r] - mnew[r]);
                    pe[ni][r] = e;
                    rs += e;
                }
#pragma unroll
                for (int off = 1; off < 16; off <<= 1)
                    rs += __shfl_xor(rs, off, 64);
                rsum[r] = rs;
            }
#pragma unroll
            for (int r = 0; r < 4; ++r) {
                float alpha = __expf(m_run[r] - mnew[r]);
                l_run[r] = l_run[r] * alpha + rsum[r];
                m_run[r] = mnew[r];
#pragma unroll
                for (int oi = 0; oi < 4; ++oi) o[oi][r] *= alpha;
            }

            // ---- P -> per-wave LDS (bf16), re-fragment for PV ----
#pragma unroll
            for (int r = 0; r < 4; ++r)
#pragma unroll
                for (int ni = 0; ni < 4; ++ni)
                    Ps[w][g * 4 + r][ni * 16 + lc] = __float2bfloat16(pe[ni][r]);

            // ---- O += P V ----
#pragma unroll
            for (int oi = 0; oi < 4; ++oi)
#pragma unroll
                for (int kk = 0; kk < 2; ++kk) {
                    int row = oi * 16 + lc;
                    bf16x8 pf = *reinterpret_cast<const bf16x8*>(&Ps[w][lc][kk * 32 + g * 8]);
                    bf16x8 vf = *reinterpret_cast<const bf16x8*>(
                        &Vt[row][(kk * 32 + g * 8) ^ (((row >> 3) & 7) << 3)]);
                    o[oi] = __builtin_amdgcn_mfma_f32_16x16x32_bf16(pf, vf, o[oi], 0, 0, 0);
                }
            __syncthreads();
        }

        // ---- epilogue: normalize, write bf16 attn output [(b*S+q)][D] ----
#pragma unroll
        for (int r = 0; r < 4; ++r) {
            float inv = 1.0f / l_run[r];
            const int qg = qt * 64 + w * 16 + g * 4 + r;
#pragma unroll
            for (int oi = 0; oi < 4; ++oi)
                outb[(size_t)(b * S_ + qg) * D_ + h * HD_ + oi * 16 + lc] =
                    __float2bfloat16(o[oi][r] * inv);
        }
    }
}

// ---------------------------------------------------------------------------
extern "C" void kernel_launch(void* const* d_in, const int* in_sizes, int n_in,
                              void* d_out, int out_size, void* d_ws, size_t ws_size,
                              hipStream_t stream) {
    const float* x  = (const float*)d_in[0];
    const float* Wq = (const float*)d_in[1];
    const float* bq = (const float*)d_in[2];
    const float* Wk = (const float*)d_in[3];
    const float* bk = (const float*)d_in[4];
    const float* Wv = (const float*)d_in[5];
    const float* bv = (const float*)d_in[6];
    const float* Wo = (const float*)d_in[7];
    const float* bo = (const float*)d_in[8];

    char* ws = (char*)d_ws;
    __hip_bfloat16* xb    = (__hip_bfloat16*)(ws);                       // 8 MB
    __hip_bfloat16* Wqkvt = (__hip_bfloat16*)(ws + (size_t)(8u  << 20)); // 6 MB
    __hip_bfloat16* Wot   = (__hip_bfloat16*)(ws + (size_t)(14u << 20)); // 2 MB
    __hip_bfloat16* qkv   = (__hip_bfloat16*)(ws + (size_t)(16u << 20)); // 24 MB
    __hip_bfloat16* attnb = (__hip_bfloat16*)(ws + (size_t)(40u << 20)); // 8 MB
    float* biasf          = (float*)(ws + (size_t)(48u << 20));          // 12 KB

    const int nX = B_ * S_ * D_;   // 4194304

    f32_to_bf16_vec<<<4096, 256, 0, stream>>>(x, xb, nX);
    transpose4_f32_to_bf16<<<dim3(32, 32, 4), 256, 0, stream>>>(
        Wq, Wk, Wv, Wo, Wqkvt, Wqkvt + D_ * D_, Wqkvt + 2 * D_ * D_, Wot);
    concat_bias<<<12, 256, 0, stream>>>(bq, bk, bv, biasf);

    // QKV projection: [4096 x 1024] @ [1024 x 3072] -> qkv (bf16)
    gemm_bt_kernel<false><<<dim3(32, 24), 256, 0, stream>>>(
        xb, Wqkvt, biasf, qkv, B_ * S_, 3 * D_, D_);

    // Attention (paired q-tiles for load balance)
    attn_kernel<<<dim3(S_ / 128, B_ * H_), 256, 0, stream>>>(qkv, attnb);

    // Output projection: [4096 x 1024] @ [1024 x 1024] -> d_out (fp32)
    gemm_bt_kernel<true><<<dim3(32, 8), 256, 0, stream>>>(
        attnb, Wot, bo, (float*)d_out, B_ * S_, D_, D_);
}

// Round 7
// 215.356 us; speedup vs baseline: 1.5112x; 1.1444x over previous
//
#include <hip/hip_runtime.h>
#include <hip/hip_bf16.h>

// Problem constants
constexpr int B_ = 2, S_ = 2048, D_ = 1024, H_ = 16, HD_ = 64;

typedef __attribute__((ext_vector_type(8))) short bf16x8;
typedef __attribute__((ext_vector_type(4))) short bf16x4;
typedef __attribute__((ext_vector_type(4))) float f32x4;

// 16x16x16 bf16 MFMA (K=16, 2-VGPR A/B operands). Guarded: builtin if present,
// else inline asm (v_mfma_f32_16x16x16_bf16 is a valid gfx950 instruction).
#if __has_builtin(__builtin_amdgcn_mfma_f32_16x16x16bf16_1k)
#define MFMA16(acc, a, b) \
    (acc) = __builtin_amdgcn_mfma_f32_16x16x16bf16_1k((a), (b), (acc), 0, 0, 0)
#else
#define MFMA16(acc, a, b) \
    asm("v_mfma_f32_16x16x16_bf16 %0, %1, %2, %0" : "+v"(acc) : "v"(a), "v"(b))
#endif

// global -> LDS direct copy, 16 B per lane.
// Dest must be linear: wave-uniform base + lane*16 (rule #21 / m104).
typedef __attribute__((address_space(1))) const unsigned char ga_t;
typedef __attribute__((address_space(3))) unsigned char la_t;
__device__ __forceinline__ void gload_lds16(const void* g, void* l) {
    __builtin_amdgcn_global_load_lds((ga_t*)g, (la_t*)l, 16, 0, 0);
}

__device__ __forceinline__ short f2bf(float x) {
    __hip_bfloat16 h = __float2bfloat16(x);
    return *reinterpret_cast<short*>(&h);
}

// ---------------------------------------------------------------------------
// fp32 -> bf16 elementwise convert (float4 in, 4x bf16 out)
// ---------------------------------------------------------------------------
__global__ void f32_to_bf16_vec(const float* __restrict__ in,
                                __hip_bfloat16* __restrict__ out, int n) {
    int i = (blockIdx.x * 256 + threadIdx.x) * 4;
    if (i >= n) return;
    float4 v = *reinterpret_cast<const float4*>(in + i);
    union { ushort4 u; __hip_bfloat16 h[4]; } pk;
    pk.h[0] = __float2bfloat16(v.x);
    pk.h[1] = __float2bfloat16(v.y);
    pk.h[2] = __float2bfloat16(v.z);
    pk.h[3] = __float2bfloat16(v.w);
    *reinterpret_cast<ushort4*>(out + i) = pk.u;
}

// ---------------------------------------------------------------------------
// Fused: 4x (1024x1024 fp32 -> transposed bf16). z selects the matrix.
// ---------------------------------------------------------------------------
__global__ void transpose4_f32_to_bf16(const float* __restrict__ w0,
                                       const float* __restrict__ w1,
                                       const float* __restrict__ w2,
                                       const float* __restrict__ w3,
                                       __hip_bfloat16* __restrict__ d0,
                                       __hip_bfloat16* __restrict__ d1,
                                       __hip_bfloat16* __restrict__ d2,
                                       __hip_bfloat16* __restrict__ d3) {
    __shared__ float tile[32][33];
    const int z = blockIdx.z;
    const float* src = z == 0 ? w0 : z == 1 ? w1 : z == 2 ? w2 : w3;
    __hip_bfloat16* dst = z == 0 ? d0 : z == 1 ? d1 : z == 2 ? d2 : d3;
    const int bx = blockIdx.x * 32;   // src col
    const int by = blockIdx.y * 32;   // src row
    const int c = threadIdx.x & 31;
    const int r0 = threadIdx.x >> 5;  // 0..7
#pragma unroll
    for (int p = 0; p < 4; ++p) {
        int r = r0 + p * 8;
        tile[r][c] = src[(size_t)(by + r) * D_ + bx + c];
    }
    __syncthreads();
#pragma unroll
    for (int p = 0; p < 4; ++p) {
        int r = r0 + p * 8;
        dst[(size_t)(bx + r) * D_ + by + c] = __float2bfloat16(tile[c][r]);
    }
}

// ---------------------------------------------------------------------------
// concat bq|bk|bv -> biasf[3072]
// ---------------------------------------------------------------------------
__global__ void concat_bias(const float* __restrict__ bq, const float* __restrict__ bk,
                            const float* __restrict__ bv, float* __restrict__ dst) {
    int i = blockIdx.x * 256 + threadIdx.x;   // 12 blocks * 256 = 3072
    float v = (i < 1024) ? bq[i] : (i < 2048) ? bk[i - 1024] : bv[i - 2048];
    dst[i] = v;
}

// ---------------------------------------------------------------------------
// bf16 GEMM: C[M][N] = A[M][K] * Bt[N][K]^T + bias[N]   (unchanged this round)
// ---------------------------------------------------------------------------
template <bool OUT_F32>
__launch_bounds__(256)
__global__ void gemm_bt_kernel(const __hip_bfloat16* __restrict__ A,
                               const __hip_bfloat16* __restrict__ Bt,
                               const float* __restrict__ bias,
                               void* __restrict__ Cout,
                               int M, int N, int K) {
    constexpr int BM = 128, BN = 128, BK = 64;
    __shared__ __hip_bfloat16 As[BM][BK];
    __shared__ __hip_bfloat16 Bs[BN][BK];

    const int tid = threadIdx.x;
    const int lane = tid & 63;
    const int w = tid >> 6;
    const int wr = w >> 1, wc = w & 1;
    const int g = lane >> 4;       // 0..3
    const int lc = lane & 15;      // 0..15
    const int m0 = blockIdx.x * BM;
    const int n0 = blockIdx.y * BN;

    const int srow = tid >> 3;                      // 0..31
    const int sc0 = (tid & 7) * 8;
    const int scol = sc0 ^ ((srow & 7) << 3);

    f32x4 acc[4][4] = {};

    for (int k0 = 0; k0 < K; k0 += BK) {
#pragma unroll
        for (int p = 0; p < 4; ++p) {
            int r = p * 32 + srow;
            gload_lds16(&A[(size_t)(m0 + r) * K + k0 + scol], &As[r][sc0]);
            gload_lds16(&Bt[(size_t)(n0 + r) * K + k0 + scol], &Bs[r][sc0]);
        }
        __syncthreads();
#pragma unroll
        for (int kk = 0; kk < 2; ++kk) {
            bf16x8 af[4], bfr[4];
#pragma unroll
            for (int mi = 0; mi < 4; ++mi) {
                int row = wr * 64 + mi * 16 + lc;
                af[mi] = *reinterpret_cast<const bf16x8*>(
                    &As[row][(kk * 32 + g * 8) ^ ((row & 7) << 3)]);
            }
#pragma unroll
            for (int ni = 0; ni < 4; ++ni) {
                int row = wc * 64 + ni * 16 + lc;
                bfr[ni] = *reinterpret_cast<const bf16x8*>(
                    &Bs[row][(kk * 32 + g * 8) ^ ((row & 7) << 3)]);
            }
#pragma unroll
            for (int mi = 0; mi < 4; ++mi)
#pragma unroll
                for (int ni = 0; ni < 4; ++ni)
                    acc[mi][ni] = __builtin_amdgcn_mfma_f32_16x16x32_bf16(af[mi], bfr[ni], acc[mi][ni], 0, 0, 0);
        }
        __syncthreads();
    }

#pragma unroll
    for (int mi = 0; mi < 4; ++mi)
#pragma unroll
        for (int r = 0; r < 4; ++r) {
            int row = m0 + wr * 64 + mi * 16 + g * 4 + r;
#pragma unroll
            for (int ni = 0; ni < 4; ++ni) {
                int col = n0 + wc * 64 + ni * 16 + lc;
                float v = acc[mi][ni][r] + bias[col];
                if (OUT_F32)
                    ((float*)Cout)[(size_t)row * N + col] = v;
                else
                    ((__hip_bfloat16*)Cout)[(size_t)row * N + col] = __float2bfloat16(v);
            }
        }
}

// ---------------------------------------------------------------------------
// Flash attention, causal + ALiBi. Swapped-operand QK^T (S^T in registers):
//   s = mfma(K, Q) -> q = lane&15 (one q-row per lane), kpos = 16*ni+4g+r.
// Softmax: in-register tree reduce + 2 shfl_xor (g-group), scalar m/l.
// PV: P-fragment in swapped layout IS the 16x16x16 B-operand layout ->
//   o[oi] = mfma16(V^T-frag, P-frag) with zero P data movement (no P LDS).
// O is transposed (hd = oi*16+4g+r, q = lane&15); epilogue packs ushort4.
// ---------------------------------------------------------------------------
__launch_bounds__(256)
__global__ void attn_kernel(const __hip_bfloat16* __restrict__ qkv,
                            __hip_bfloat16* __restrict__ outb) {
    __shared__ __hip_bfloat16 Ks[64][64];
    __shared__ __hip_bfloat16 Vt[64][72];

    const int tid = threadIdx.x;
    const int lane = tid & 63;
    const int w = tid >> 6;
    const int bh = blockIdx.y;                   // b*H + h (32)
    const int b = bh >> 4, h = bh & 15;
    const int g = lane >> 4;    // 0..3
    const int lc = lane & 15;   // 0..15
    const int lq = w * 16 + lc; // q-row within the 64-row tile

    const float slope = exp2f(-0.5f * (float)(h + 1));   // (2^(-8/16))^(h+1)

    const size_t rowstride = 3 * D_;
    const size_t base = (size_t)b * S_ * rowstride + h * HD_;

    const int srow = tid >> 3;           // 0..31
    const int sc0 = (tid & 7) * 8;
    const int kscol = sc0 ^ ((srow & 7) << 3);   // K source pre-swizzle
    const int vwsz = (tid & 7) << 3;             // Vt write col-swizzle key

#pragma unroll 1
    for (int phase = 0; phase < 2; ++phase) {
        const int qt = phase == 0 ? (31 - blockIdx.x) : blockIdx.x;
        const int qg = qt * 64 + lq;             // global q row

        // Q fragments (B-operand layout: n=q=lc, k contiguous 8g+j)
        bf16x8 aq[2];
#pragma unroll
        for (int kk = 0; kk < 2; ++kk)
            aq[kk] = *reinterpret_cast<const bf16x8*>(
                &qkv[base + (size_t)qg * rowstride + kk * 32 + g * 8]);

        f32x4 o[4] = {};
        float m_run = -3e38f, l_run = 0.f;

        for (int kt = 0; kt <= qt; ++kt) {
            // ---- stage K (global_load_lds, linear dest) ----
#pragma unroll
            for (int p = 0; p < 2; ++p) {
                int r = p * 32 + srow;
                gload_lds16(&qkv[base + (size_t)(kt * 64 + r) * rowstride + D_ + kscol],
                            &Ks[r][sc0]);
            }
            // ---- stage V transposed+swizzled (reg-staged) ----
#pragma unroll
            for (int p = 0; p < 2; ++p) {
                int r = p * 32 + srow;
                uint4 vv = *reinterpret_cast<const uint4*>(
                    &qkv[base + (size_t)(kt * 64 + r) * rowstride + 2 * D_ + sc0]);
                const __hip_bfloat16* ve = reinterpret_cast<const __hip_bfloat16*>(&vv);
#pragma unroll
                for (int j = 0; j < 8; ++j)
                    Vt[sc0 + j][r ^ vwsz] = ve[j];   // (row>>3)&7 == tid&7
            }
            __syncthreads();

            // ---- S^T = (K Q^T): lane holds q=lc, kpos=16ni+4g+r ----
            f32x4 s[4] = {};
#pragma unroll
            for (int ni = 0; ni < 4; ++ni)
#pragma unroll
                for (int kk = 0; kk < 2; ++kk) {
                    int row = ni * 16 + lc;   // kpos for the A-operand (K rows)
                    bf16x8 kf = *reinterpret_cast<const bf16x8*>(
                        &Ks[row][(kk * 32 + g * 8) ^ ((row & 7) << 3)]);
                    s[ni] = __builtin_amdgcn_mfma_f32_16x16x32_bf16(kf, aq[kk], s[ni], 0, 0, 0);
                }

            // ---- scale + alibi + mask (all in registers) ----
            const bool diag = (kt == qt);
            const float dlt = (float)(kt * 64 - qg);
            float v[16];
#pragma unroll
            for (int ni = 0; ni < 4; ++ni)
#pragma unroll
                for (int r = 0; r < 4; ++r) {
                    const int koff = 16 * ni + 4 * g + r;
                    float t = fmaf(s[ni][r], 0.125f, slope * (dlt + (float)koff));
                    if (diag && koff > lq) t = -3e38f;
                    v[ni * 4 + r] = t;
                }

            // ---- row max: in-lane tree + 2-step g-group butterfly ----
            float t8[8], t4[4];
#pragma unroll
            for (int i = 0; i < 8; ++i) t8[i] = fmaxf(v[i], v[i + 8]);
#pragma unroll
            for (int i = 0; i < 4; ++i) t4[i] = fmaxf(t8[i], t8[i + 4]);
            float rm = fmaxf(fmaxf(t4[0], t4[1]), fmaxf(t4[2], t4[3]));
            rm = fmaxf(rm, __shfl_xor(rm, 16, 64));
            rm = fmaxf(rm, __shfl_xor(rm, 32, 64));

            const float mnew = fmaxf(m_run, rm);
            const float alpha = __expf(m_run - mnew);
            m_run = mnew;

            // ---- exp + row sum ----
#pragma unroll
            for (int i = 0; i < 16; ++i) v[i] = __expf(v[i] - mnew);
            float s8[8], s4[4];
#pragma unroll
            for (int i = 0; i < 8; ++i) s8[i] = v[i] + v[i + 8];
#pragma unroll
            for (int i = 0; i < 4; ++i) s4[i] = s8[i] + s8[i + 4];
            float rs = (s4[0] + s4[1]) + (s4[2] + s4[3]);
            rs += __shfl_xor(rs, 16, 64);
            rs += __shfl_xor(rs, 32, 64);
            l_run = l_run * alpha + rs;

            // ---- rescale O, pack P to bf16 (k = 4g+r == mfma16 B-layout) ----
            bf16x4 pb[4];
#pragma unroll
            for (int ni = 0; ni < 4; ++ni) {
#pragma unroll
                for (int r = 0; r < 4; ++r) {
                    o[ni][r] *= alpha;   // o[ni] reused as oi index below; same count
                    pb[ni][r] = f2bf(v[ni * 4 + r]);
                }
            }

            // ---- O^T += V^T P^T : o[oi] rows hd=oi*16+4g+r, col q=lc ----
#pragma unroll
            for (int oi = 0; oi < 4; ++oi) {
                const int row = oi * 16 + lc;                  // hd
                const int key = ((row >> 3) & 7) << 3;
#pragma unroll
                for (int ni = 0; ni < 4; ++ni) {
                    bf16x4 vf = *reinterpret_cast<const bf16x4*>(
                        &Vt[row][(ni * 16 + 4 * g) ^ key]);
                    MFMA16(o[oi], vf, pb[ni]);
                }
            }
            __syncthreads();
        }

        // ---- epilogue: normalize, pack 4 contiguous hd per ushort4 store ----
        const float inv = 1.0f / l_run;
#pragma unroll
        for (int oi = 0; oi < 4; ++oi) {
            union { ushort4 u; short s[4]; } pk;
#pragma unroll
            for (int r = 0; r < 4; ++r) pk.s[r] = f2bf(o[oi][r] * inv);
            *reinterpret_cast<ushort4*>(
                &outb[(size_t)(b * S_ + qg) * D_ + h * HD_ + oi * 16 + 4 * g]) = pk.u;
        }
    }
}

// ---------------------------------------------------------------------------
extern "C" void kernel_launch(void* const* d_in, const int* in_sizes, int n_in,
                              void* d_out, int out_size, void* d_ws, size_t ws_size,
                              hipStream_t stream) {
    const float* x  = (const float*)d_in[0];
    const float* Wq = (const float*)d_in[1];
    const float* bq = (const float*)d_in[2];
    const float* Wk = (const float*)d_in[3];
    const float* bk = (const float*)d_in[4];
    const float* Wv = (const float*)d_in[5];
    const float* bv = (const float*)d_in[6];
    const float* Wo = (const float*)d_in[7];
    const float* bo = (const float*)d_in[8];

    char* ws = (char*)d_ws;
    __hip_bfloat16* xb    = (__hip_bfloat16*)(ws);                       // 8 MB
    __hip_bfloat16* Wqkvt = (__hip_bfloat16*)(ws + (size_t)(8u  << 20)); // 6 MB
    __hip_bfloat16* Wot   = (__hip_bfloat16*)(ws + (size_t)(14u << 20)); // 2 MB
    __hip_bfloat16* qkv   = (__hip_bfloat16*)(ws + (size_t)(16u << 20)); // 24 MB
    __hip_bfloat16* attnb = (__hip_bfloat16*)(ws + (size_t)(40u << 20)); // 8 MB
    float* biasf          = (float*)(ws + (size_t)(48u << 20));          // 12 KB

    const int nX = B_ * S_ * D_;   // 4194304

    f32_to_bf16_vec<<<4096, 256, 0, stream>>>(x, xb, nX);
    transpose4_f32_to_bf16<<<dim3(32, 32, 4), 256, 0, stream>>>(
        Wq, Wk, Wv, Wo, Wqkvt, Wqkvt + D_ * D_, Wqkvt + 2 * D_ * D_, Wot);
    concat_bias<<<12, 256, 0, stream>>>(bq, bk, bv, biasf);

    // QKV projection: [4096 x 1024] @ [1024 x 3072] -> qkv (bf16)
    gemm_bt_kernel<false><<<dim3(32, 24), 256, 0, stream>>>(
        xb, Wqkvt, biasf, qkv, B_ * S_, 3 * D_, D_);

    // Attention (paired q-tiles for load balance)
    attn_kernel<<<dim3(S_ / 128, B_ * H_), 256, 0, stream>>>(qkv, attnb);

    // Output projection: [4096 x 1024] @ [1024 x 1024] -> d_out (fp32)
    gemm_bt_kernel<true><<<dim3(32, 8), 256, 0, stream>>>(
        attnb, Wot, bo, (float*)d_out, B_ * S_, D_, D_);
}

// Round 9
// 209.465 us; speedup vs baseline: 1.5536x; 1.0281x over previous
//
#include <hip/hip_runtime.h>
#include <hip/hip_bf16.h>

// Problem constants
constexpr int B_ = 2, S_ = 2048, D_ = 1024, H_ = 16, HD_ = 64;

typedef __attribute__((ext_vector_type(8))) short bf16x8;
typedef __attribute__((ext_vector_type(4))) short bf16x4;
typedef __attribute__((ext_vector_type(4))) float f32x4;

// 16x16x16 bf16 MFMA (K=16, 2-VGPR A/B operands).
#if __has_builtin(__builtin_amdgcn_mfma_f32_16x16x16bf16_1k)
#define MFMA16(acc, a, b) \
    (acc) = __builtin_amdgcn_mfma_f32_16x16x16bf16_1k((a), (b), (acc), 0, 0, 0)
#else
#define MFMA16(acc, a, b) \
    asm("v_mfma_f32_16x16x16_bf16 %0, %1, %2, %0" : "+v"(acc) : "v"(a), "v"(b))
#endif

// global -> LDS direct copy, 16 B per lane (dest linear: base + lane*16).
typedef __attribute__((address_space(1))) const unsigned char ga_t;
typedef __attribute__((address_space(3))) unsigned char la_t;
__device__ __forceinline__ void gload_lds16(const void* g, void* l) {
    __builtin_amdgcn_global_load_lds((ga_t*)g, (la_t*)l, 16, 0, 0);
}

__device__ __forceinline__ short f2bf(float x) {
    __hip_bfloat16 h = __float2bfloat16(x);
    return *reinterpret_cast<short*>(&h);
}

// ---------------------------------------------------------------------------
// fp32 -> bf16 elementwise convert
// ---------------------------------------------------------------------------
__global__ void f32_to_bf16_vec(const float* __restrict__ in,
                                __hip_bfloat16* __restrict__ out, int n) {
    int i = (blockIdx.x * 256 + threadIdx.x) * 4;
    if (i >= n) return;
    float4 v = *reinterpret_cast<const float4*>(in + i);
    union { ushort4 u; __hip_bfloat16 h[4]; } pk;
    pk.h[0] = __float2bfloat16(v.x);
    pk.h[1] = __float2bfloat16(v.y);
    pk.h[2] = __float2bfloat16(v.z);
    pk.h[3] = __float2bfloat16(v.w);
    *reinterpret_cast<ushort4*>(out + i) = pk.u;
}

// ---------------------------------------------------------------------------
// Fused: 4x (1024x1024 fp32 -> transposed bf16). z selects the matrix.
// ---------------------------------------------------------------------------
__global__ void transpose4_f32_to_bf16(const float* __restrict__ w0,
                                       const float* __restrict__ w1,
                                       const float* __restrict__ w2,
                                       const float* __restrict__ w3,
                                       __hip_bfloat16* __restrict__ d0,
                                       __hip_bfloat16* __restrict__ d1,
                                       __hip_bfloat16* __restrict__ d2,
                                       __hip_bfloat16* __restrict__ d3) {
    __shared__ float tile[32][33];
    const int z = blockIdx.z;
    const float* src = z == 0 ? w0 : z == 1 ? w1 : z == 2 ? w2 : w3;
    __hip_bfloat16* dst = z == 0 ? d0 : z == 1 ? d1 : z == 2 ? d2 : d3;
    const int bx = blockIdx.x * 32;   // src col
    const int by = blockIdx.y * 32;   // src row
    const int c = threadIdx.x & 31;
    const int r0 = threadIdx.x >> 5;  // 0..7
#pragma unroll
    for (int p = 0; p < 4; ++p) {
        int r = r0 + p * 8;
        tile[r][c] = src[(size_t)(by + r) * D_ + bx + c];
    }
    __syncthreads();
#pragma unroll
    for (int p = 0; p < 4; ++p) {
        int r = r0 + p * 8;
        dst[(size_t)(bx + r) * D_ + by + c] = __float2bfloat16(tile[c][r]);
    }
}

// ---------------------------------------------------------------------------
// concat bq|bk|bv -> biasf[3072]
// ---------------------------------------------------------------------------
__global__ void concat_bias(const float* __restrict__ bq, const float* __restrict__ bk,
                            const float* __restrict__ bv, float* __restrict__ dst) {
    int i = blockIdx.x * 256 + threadIdx.x;   // 12 blocks * 256 = 3072
    float v = (i < 1024) ? bq[i] : (i < 2048) ? bk[i - 1024] : bv[i - 2048];
    dst[i] = v;
}

// ---------------------------------------------------------------------------
// bf16 GEMM: C[M][N] = A[M][K] * Bt[N][K]^T + bias[N]
// 128xBN_ tile, BK=64, gload_lds w16, both-sides XOR swizzle.
// BN_=128: 2x2 waves, 64 cols each (QKV).  BN_=64: 2x2 waves, 32 cols (Oproj,
// doubles block count -> 2 blocks/CU instead of 1).
// ---------------------------------------------------------------------------
template <bool OUT_F32, int BN_>
__launch_bounds__(256)
__global__ void gemm_bt_kernel(const __hip_bfloat16* __restrict__ A,
                               const __hip_bfloat16* __restrict__ Bt,
                               const float* __restrict__ bias,
                               void* __restrict__ Cout,
                               int M, int N, int K) {
    constexpr int BM = 128, BK = 64;
    constexpr int NI = BN_ / 32;            // per-wave 16-col fragments
    __shared__ __hip_bfloat16 As[BM][BK];
    __shared__ __hip_bfloat16 Bs[BN_][BK];

    const int tid = threadIdx.x;
    const int lane = tid & 63;
    const int w = tid >> 6;
    const int wr = w >> 1, wc = w & 1;
    const int g = lane >> 4;       // 0..3
    const int lc = lane & 15;      // 0..15
    const int m0 = blockIdx.x * BM;
    const int n0 = blockIdx.y * BN_;

    const int srow = tid >> 3;                      // 0..31
    const int sc0 = (tid & 7) * 8;
    const int scol = sc0 ^ ((srow & 7) << 3);

    f32x4 acc[4][NI] = {};

    for (int k0 = 0; k0 < K; k0 += BK) {
#pragma unroll
        for (int p = 0; p < 4; ++p) {
            int r = p * 32 + srow;
            gload_lds16(&A[(size_t)(m0 + r) * K + k0 + scol], &As[r][sc0]);
        }
#pragma unroll
        for (int p = 0; p < BN_ / 32; ++p) {
            int r = p * 32 + srow;
            gload_lds16(&Bt[(size_t)(n0 + r) * K + k0 + scol], &Bs[r][sc0]);
        }
        __syncthreads();
#pragma unroll
        for (int kk = 0; kk < 2; ++kk) {
            bf16x8 af[4], bfr[NI];
#pragma unroll
            for (int mi = 0; mi < 4; ++mi) {
                int row = wr * 64 + mi * 16 + lc;
                af[mi] = *reinterpret_cast<const bf16x8*>(
                    &As[row][(kk * 32 + g * 8) ^ ((row & 7) << 3)]);
            }
#pragma unroll
            for (int ni = 0; ni < NI; ++ni) {
                int row = wc * (BN_ / 2) + ni * 16 + lc;
                bfr[ni] = *reinterpret_cast<const bf16x8*>(
                    &Bs[row][(kk * 32 + g * 8) ^ ((row & 7) << 3)]);
            }
#pragma unroll
            for (int mi = 0; mi < 4; ++mi)
#pragma unroll
                for (int ni = 0; ni < NI; ++ni)
                    acc[mi][ni] = __builtin_amdgcn_mfma_f32_16x16x32_bf16(af[mi], bfr[ni], acc[mi][ni], 0, 0, 0);
        }
        __syncthreads();
    }

#pragma unroll
    for (int mi = 0; mi < 4; ++mi)
#pragma unroll
        for (int r = 0; r < 4; ++r) {
            int row = m0 + wr * 64 + mi * 16 + g * 4 + r;
#pragma unroll
            for (int ni = 0; ni < NI; ++ni) {
                int col = n0 + wc * (BN_ / 2) + ni * 16 + lc;
                float v = acc[mi][ni][r] + bias[col];
                if (OUT_F32)
                    ((float*)Cout)[(size_t)row * N + col] = v;
                else
                    ((__hip_bfloat16*)Cout)[(size_t)row * N + col] = __float2bfloat16(v);
            }
        }
}

// ---------------------------------------------------------------------------
// Flash attention, causal + ALiBi.  Swapped-operand QK^T, in-register softmax
// (exp2 domain), zero-movement PV via mfma16.
// This round: unpaired grid (32 bh fastest x 32 qt, longest-first) and
// double-buffered K/V with prefetch-before-compute (T14-style async stage):
//   top of iter: issue K gload_lds(kt+1, buf^1) + V global loads(kt+1)->regs
//   compute(kt) from buf      (hides the staging latency)
//   ds_write V(kt+1)->buf^1, barrier.
// ---------------------------------------------------------------------------
__launch_bounds__(256)
__global__ void attn_kernel(const __hip_bfloat16* __restrict__ qkv,
                            __hip_bfloat16* __restrict__ outb) {
    __shared__ __hip_bfloat16 Ks[2][64][64];
    __shared__ __hip_bfloat16 Vt[2][64][72];

    const int tid = threadIdx.x;
    const int lane = tid & 63;
    const int w = tid >> 6;
    const int bh = blockIdx.x;                   // b*H + h (32), fastest dim
    const int b = bh >> 4, h = bh & 15;
    const int g = lane >> 4;    // 0..3
    const int lc = lane & 15;   // 0..15
    const int lq = w * 16 + lc; // q-row within the 64-row tile

    constexpr float LOG2E = 1.44269504088896f;
    constexpr float SC = 0.125f * LOG2E;                       // qk scale in log2 domain
    const float slope2 = exp2f(-0.5f * (float)(h + 1)) * LOG2E; // alibi slope in log2 domain

    const size_t rowstride = 3 * D_;
    const size_t base = (size_t)b * S_ * rowstride + h * HD_;

    const int srow = tid >> 3;           // 0..31
    const int sc0 = (tid & 7) * 8;
    const int kscol = sc0 ^ ((srow & 7) << 3);   // K source pre-swizzle
    const int vwsz = (tid & 7) << 3;             // Vt write col-swizzle key

    const int qt = 31 - blockIdx.y;              // longest-first dispatch
    const int qg = qt * 64 + lq;                 // global q row

    // Q fragments (B-operand layout: n=q=lc, k contiguous 8g+j)
    bf16x8 aq[2];
#pragma unroll
    for (int kk = 0; kk < 2; ++kk)
        aq[kk] = *reinterpret_cast<const bf16x8*>(
            &qkv[base + (size_t)qg * rowstride + kk * 32 + g * 8]);

    // hoisted alibi per-slot offsets: slope2 * koff
    float ab[16];
#pragma unroll
    for (int ni = 0; ni < 4; ++ni)
#pragma unroll
        for (int r = 0; r < 4; ++r)
            ab[ni * 4 + r] = slope2 * (float)(16 * ni + 4 * g + r);

    f32x4 o[4] = {};
    float m_run = -3e38f, l_run = 0.f;

    // ---- prologue: stage tile 0 into buf 0 ----
#pragma unroll
    for (int p = 0; p < 2; ++p) {
        int r = p * 32 + srow;
        gload_lds16(&qkv[base + (size_t)r * rowstride + D_ + kscol], &Ks[0][r][sc0]);
        uint4 vv = *reinterpret_cast<const uint4*>(
            &qkv[base + (size_t)r * rowstride + 2 * D_ + sc0]);
        const __hip_bfloat16* ve = reinterpret_cast<const __hip_bfloat16*>(&vv);
#pragma unroll
        for (int j = 0; j < 8; ++j)
            Vt[0][sc0 + j][r ^ vwsz] = ve[j];
    }
    __syncthreads();

    int cur = 0;
    for (int kt = 0; kt <= qt; ++kt) {
        // ---- prefetch kt+1 (issue early; latency hides under compute) ----
        const bool havepre = (kt < qt);
        uint4 vpre[2];
        if (havepre) {
#pragma unroll
            for (int p = 0; p < 2; ++p) {
                int r = p * 32 + srow;
                gload_lds16(&qkv[base + (size_t)((kt + 1) * 64 + r) * rowstride + D_ + kscol],
                            &Ks[cur ^ 1][r][sc0]);
                vpre[p] = *reinterpret_cast<const uint4*>(
                    &qkv[base + (size_t)((kt + 1) * 64 + r) * rowstride + 2 * D_ + sc0]);
            }
        }

        // ---- S^T = (K Q^T): lane holds q=lc, kpos=16ni+4g+r ----
        f32x4 s[4] = {};
#pragma unroll
        for (int ni = 0; ni < 4; ++ni)
#pragma unroll
            for (int kk = 0; kk < 2; ++kk) {
                int row = ni * 16 + lc;
                bf16x8 kf = *reinterpret_cast<const bf16x8*>(
                    &Ks[cur][row][(kk * 32 + g * 8) ^ ((row & 7) << 3)]);
                s[ni] = __builtin_amdgcn_mfma_f32_16x16x32_bf16(kf, aq[kk], s[ni], 0, 0, 0);
            }

        // ---- scale + alibi + mask (log2 domain) ----
        const bool diag = (kt == qt);
        const float b0 = slope2 * (float)(kt * 64 - qg);
        float v[16];
#pragma unroll
        for (int ni = 0; ni < 4; ++ni)
#pragma unroll
            for (int r = 0; r < 4; ++r) {
                const int koff = 16 * ni + 4 * g + r;
                float t = fmaf(s[ni][r], SC, b0 + ab[ni * 4 + r]);
                if (diag && koff > lq) t = -3e38f;
                v[ni * 4 + r] = t;
            }

        // ---- row max: in-lane tree + 2-step butterfly ----
        float t8[8], t4[4];
#pragma unroll
        for (int i = 0; i < 8; ++i) t8[i] = fmaxf(v[i], v[i + 8]);
#pragma unroll
        for (int i = 0; i < 4; ++i) t4[i] = fmaxf(t8[i], t8[i + 4]);
        float rm = fmaxf(fmaxf(t4[0], t4[1]), fmaxf(t4[2], t4[3]));
        rm = fmaxf(rm, __shfl_xor(rm, 16, 64));
        rm = fmaxf(rm, __shfl_xor(rm, 32, 64));

        const float mnew = fmaxf(m_run, rm);
        const float alpha = exp2f(m_run - mnew);
        m_run = mnew;

        // ---- exp2 + row sum ----
#pragma unroll
        for (int i = 0; i < 16; ++i) v[i] = exp2f(v[i] - mnew);
        float s8[8], s4[4];
#pragma unroll
        for (int i = 0; i < 8; ++i) s8[i] = v[i] + v[i + 8];
#pragma unroll
        for (int i = 0; i < 4; ++i) s4[i] = s8[i] + s8[i + 4];
        float rs = (s4[0] + s4[1]) + (s4[2] + s4[3]);
        rs += __shfl_xor(rs, 16, 64);
        rs += __shfl_xor(rs, 32, 64);
        l_run = l_run * alpha + rs;

        // ---- rescale O, pack P to bf16 (k = 4g+r == mfma16 B-layout) ----
        bf16x4 pb[4];
#pragma unroll
        for (int ni = 0; ni < 4; ++ni)
#pragma unroll
            for (int r = 0; r < 4; ++r) {
                o[ni][r] *= alpha;
                pb[ni][r] = f2bf(v[ni * 4 + r]);
            }

        // ---- O^T += V^T P^T ----
#pragma unroll
        for (int oi = 0; oi < 4; ++oi) {
            const int row = oi * 16 + lc;                  // hd
            const int key = ((row >> 3) & 7) << 3;
#pragma unroll
            for (int ni = 0; ni < 4; ++ni) {
                bf16x4 vf = *reinterpret_cast<const bf16x4*>(
                    &Vt[cur][row][(ni * 16 + 4 * g) ^ key]);
                MFMA16(o[oi], vf, pb[ni]);
            }
        }

        // ---- write prefetched V into buf^1, then hand off ----
        if (havepre) {
#pragma unroll
            for (int p = 0; p < 2; ++p) {
                int r = p * 32 + srow;
                const __hip_bfloat16* ve = reinterpret_cast<const __hip_bfloat16*>(&vpre[p]);
#pragma unroll
                for (int j = 0; j < 8; ++j)
                    Vt[cur ^ 1][sc0 + j][r ^ vwsz] = ve[j];
            }
        }
        __syncthreads();
        cur ^= 1;
    }

    // ---- epilogue: normalize, pack 4 contiguous hd per ushort4 store ----
    const float inv = 1.0f / l_run;
#pragma unroll
    for (int oi = 0; oi < 4; ++oi) {
        union { ushort4 u; short s[4]; } pk;
#pragma unroll
        for (int r = 0; r < 4; ++r) pk.s[r] = f2bf(o[oi][r] * inv);
        *reinterpret_cast<ushort4*>(
            &outb[(size_t)(b * S_ + qg) * D_ + h * HD_ + oi * 16 + 4 * g]) = pk.u;
    }
}

// ---------------------------------------------------------------------------
extern "C" void kernel_launch(void* const* d_in, const int* in_sizes, int n_in,
                              void* d_out, int out_size, void* d_ws, size_t ws_size,
                              hipStream_t stream) {
    const float* x  = (const float*)d_in[0];
    const float* Wq = (const float*)d_in[1];
    const float* bq = (const float*)d_in[2];
    const float* Wk = (const float*)d_in[3];
    const float* bk = (const float*)d_in[4];
    const float* Wv = (const float*)d_in[5];
    const float* bv = (const float*)d_in[6];
    const float* Wo = (const float*)d_in[7];
    const float* bo = (const float*)d_in[8];

    char* ws = (char*)d_ws;
    __hip_bfloat16* xb    = (__hip_bfloat16*)(ws);                       // 8 MB
    __hip_bfloat16* Wqkvt = (__hip_bfloat16*)(ws + (size_t)(8u  << 20)); // 6 MB
    __hip_bfloat16* Wot   = (__hip_bfloat16*)(ws + (size_t)(14u << 20)); // 2 MB
    __hip_bfloat16* qkv   = (__hip_bfloat16*)(ws + (size_t)(16u << 20)); // 24 MB
    __hip_bfloat16* attnb = (__hip_bfloat16*)(ws + (size_t)(40u << 20)); // 8 MB
    float* biasf          = (float*)(ws + (size_t)(48u << 20));          // 12 KB

    const int nX = B_ * S_ * D_;   // 4194304

    f32_to_bf16_vec<<<4096, 256, 0, stream>>>(x, xb, nX);
    transpose4_f32_to_bf16<<<dim3(32, 32, 4), 256, 0, stream>>>(
        Wq, Wk, Wv, Wo, Wqkvt, Wqkvt + D_ * D_, Wqkvt + 2 * D_ * D_, Wot);
    concat_bias<<<12, 256, 0, stream>>>(bq, bk, bv, biasf);

    // QKV projection: [4096 x 1024] @ [1024 x 3072] -> qkv (bf16)
    gemm_bt_kernel<false, 128><<<dim3(32, 24), 256, 0, stream>>>(
        xb, Wqkvt, biasf, qkv, B_ * S_, 3 * D_, D_);

    // Attention: grid (bh fastest, qt longest-first)
    attn_kernel<<<dim3(B_ * H_, S_ / 64), 256, 0, stream>>>(qkv, attnb);

    // Output projection: [4096 x 1024] @ [1024 x 1024] -> d_out (fp32), BN=64
    gemm_bt_kernel<true, 64><<<dim3(32, 16), 256, 0, stream>>>(
        attnb, Wot, bo, (float*)d_out, B_ * S_, D_, D_);
}

// Round 13
// 194.058 us; speedup vs baseline: 1.6770x; 1.0794x over previous
//
#include <hip/hip_runtime.h>
#include <hip/hip_bf16.h>

// Problem constants
constexpr int B_ = 2, S_ = 2048, D_ = 1024, H_ = 16, HD_ = 64;

typedef __attribute__((ext_vector_type(8))) short bf16x8;
typedef __attribute__((ext_vector_type(4))) short bf16x4;
typedef __attribute__((ext_vector_type(4))) float f32x4;

// 16x16x16 bf16 MFMA (K=16, 2-VGPR A/B operands).
#if __has_builtin(__builtin_amdgcn_mfma_f32_16x16x16bf16_1k)
#define MFMA16(acc, a, b) \
    (acc) = __builtin_amdgcn_mfma_f32_16x16x16bf16_1k((a), (b), (acc), 0, 0, 0)
#else
#define MFMA16(acc, a, b) \
    asm("v_mfma_f32_16x16x16_bf16 %0, %1, %2, %0" : "+v"(acc) : "v"(a), "v"(b))
#endif

// global -> LDS direct copy, 16 B per lane (dest linear: base + lane*16).
typedef __attribute__((address_space(1))) const unsigned char ga_t;
typedef __attribute__((address_space(3))) unsigned char la_t;
__device__ __forceinline__ void gload_lds16(const void* g, void* l) {
    __builtin_amdgcn_global_load_lds((ga_t*)g, (la_t*)l, 16, 0, 0);
}

__device__ __forceinline__ short f2bf(float x) {
    __hip_bfloat16 h = __float2bfloat16(x);
    return *reinterpret_cast<short*>(&h);
}

// ---------------------------------------------------------------------------
// fp32 -> bf16 elementwise convert
// ---------------------------------------------------------------------------
__global__ void f32_to_bf16_vec(const float* __restrict__ in,
                                __hip_bfloat16* __restrict__ out, int n) {
    int i = (blockIdx.x * 256 + threadIdx.x) * 4;
    if (i >= n) return;
    float4 v = *reinterpret_cast<const float4*>(in + i);
    union { ushort4 u; __hip_bfloat16 h[4]; } pk;
    pk.h[0] = __float2bfloat16(v.x);
    pk.h[1] = __float2bfloat16(v.y);
    pk.h[2] = __float2bfloat16(v.z);
    pk.h[3] = __float2bfloat16(v.w);
    *reinterpret_cast<ushort4*>(out + i) = pk.u;
}

// ---------------------------------------------------------------------------
// Fused: 4x (1024x1024 fp32 -> transposed bf16). z selects the matrix.
// ---------------------------------------------------------------------------
__global__ void transpose4_f32_to_bf16(const float* __restrict__ w0,
                                       const float* __restrict__ w1,
                                       const float* __restrict__ w2,
                                       const float* __restrict__ w3,
                                       __hip_bfloat16* __restrict__ d0,
                                       __hip_bfloat16* __restrict__ d1,
                                       __hip_bfloat16* __restrict__ d2,
                                       __hip_bfloat16* __restrict__ d3) {
    __shared__ float tile[32][33];
    const int z = blockIdx.z;
    const float* src = z == 0 ? w0 : z == 1 ? w1 : z == 2 ? w2 : w3;
    __hip_bfloat16* dst = z == 0 ? d0 : z == 1 ? d1 : z == 2 ? d2 : d3;
    const int bx = blockIdx.x * 32;   // src col
    const int by = blockIdx.y * 32;   // src row
    const int c = threadIdx.x & 31;
    const int r0 = threadIdx.x >> 5;  // 0..7
#pragma unroll
    for (int p = 0; p < 4; ++p) {
        int r = r0 + p * 8;
        tile[r][c] = src[(size_t)(by + r) * D_ + bx + c];
    }
    __syncthreads();
#pragma unroll
    for (int p = 0; p < 4; ++p) {
        int r = r0 + p * 8;
        dst[(size_t)(bx + r) * D_ + by + c] = __float2bfloat16(tile[c][r]);
    }
}

// ---------------------------------------------------------------------------
// concat bq|bk|bv -> biasf[3072]
// ---------------------------------------------------------------------------
__global__ void concat_bias(const float* __restrict__ bq, const float* __restrict__ bk,
                            const float* __restrict__ bv, float* __restrict__ dst) {
    int i = blockIdx.x * 256 + threadIdx.x;   // 12 blocks * 256 = 3072
    float v = (i < 1024) ? bq[i] : (i < 2048) ? bk[i - 1024] : bv[i - 2048];
    dst[i] = v;
}

// ---------------------------------------------------------------------------
// bf16 GEMM: C[M][N] = A[M][K] * Bt[N][K]^T + bias[N]   (unchanged)
// ---------------------------------------------------------------------------
template <bool OUT_F32, int BN_>
__launch_bounds__(256)
__global__ void gemm_bt_kernel(const __hip_bfloat16* __restrict__ A,
                               const __hip_bfloat16* __restrict__ Bt,
                               const float* __restrict__ bias,
                               void* __restrict__ Cout,
                               int M, int N, int K) {
    constexpr int BM = 128, BK = 64;
    constexpr int NI = BN_ / 32;            // per-wave 16-col fragments
    __shared__ __hip_bfloat16 As[BM][BK];
    __shared__ __hip_bfloat16 Bs[BN_][BK];

    const int tid = threadIdx.x;
    const int lane = tid & 63;
    const int w = tid >> 6;
    const int wr = w >> 1, wc = w & 1;
    const int g = lane >> 4;       // 0..3
    const int lc = lane & 15;      // 0..15
    const int m0 = blockIdx.x * BM;
    const int n0 = blockIdx.y * BN_;

    const int srow = tid >> 3;                      // 0..31
    const int sc0 = (tid & 7) * 8;
    const int scol = sc0 ^ ((srow & 7) << 3);

    f32x4 acc[4][NI] = {};

    for (int k0 = 0; k0 < K; k0 += BK) {
#pragma unroll
        for (int p = 0; p < 4; ++p) {
            int r = p * 32 + srow;
            gload_lds16(&A[(size_t)(m0 + r) * K + k0 + scol], &As[r][sc0]);
        }
#pragma unroll
        for (int p = 0; p < BN_ / 32; ++p) {
            int r = p * 32 + srow;
            gload_lds16(&Bt[(size_t)(n0 + r) * K + k0 + scol], &Bs[r][sc0]);
        }
        __syncthreads();
#pragma unroll
        for (int kk = 0; kk < 2; ++kk) {
            bf16x8 af[4], bfr[NI];
#pragma unroll
            for (int mi = 0; mi < 4; ++mi) {
                int row = wr * 64 + mi * 16 + lc;
                af[mi] = *reinterpret_cast<const bf16x8*>(
                    &As[row][(kk * 32 + g * 8) ^ ((row & 7) << 3)]);
            }
#pragma unroll
            for (int ni = 0; ni < NI; ++ni) {
                int row = wc * (BN_ / 2) + ni * 16 + lc;
                bfr[ni] = *reinterpret_cast<const bf16x8*>(
                    &Bs[row][(kk * 32 + g * 8) ^ ((row & 7) << 3)]);
            }
#pragma unroll
            for (int mi = 0; mi < 4; ++mi)
#pragma unroll
                for (int ni = 0; ni < NI; ++ni)
                    acc[mi][ni] = __builtin_amdgcn_mfma_f32_16x16x32_bf16(af[mi], bfr[ni], acc[mi][ni], 0, 0, 0);
        }
        __syncthreads();
    }

#pragma unroll
    for (int mi = 0; mi < 4; ++mi)
#pragma unroll
        for (int r = 0; r < 4; ++r) {
            int row = m0 + wr * 64 + mi * 16 + g * 4 + r;
#pragma unroll
            for (int ni = 0; ni < NI; ++ni) {
                int col = n0 + wc * (BN_ / 2) + ni * 16 + lc;
                float v = acc[mi][ni][r] + bias[col];
                if (OUT_F32)
                    ((float*)Cout)[(size_t)row * N + col] = v;
                else
                    ((__hip_bfloat16*)Cout)[(size_t)row * N + col] = __float2bfloat16(v);
            }
        }
}

// ---------------------------------------------------------------------------
// Flash attention, causal + ALiBi.  Swapped-operand QK^T, in-register softmax
// (exp2 domain), zero-movement PV via mfma16, double-buffered K/V.
// VALU diet:
//  - BACKWARD kt iteration: diag tile first. ALiBi decays with distance, so
//    the running max is set by the diag tile and later tiles ~never raise it.
//  - Exact rescale-skip: if !__any(rm > m_run-b0) then alpha==1 -> skip the
//    O-rescale/l-mul entirely (bit-exact, no threshold).
//  - Diag iteration peeled -> main loop has NO causal-mask ops.
//  - b0 (per-tile ALiBi offset) folded into the subtracted max, not per-elem.
// ---------------------------------------------------------------------------
__launch_bounds__(256)
__global__ void attn_kernel(const __hip_bfloat16* __restrict__ qkv,
                            __hip_bfloat16* __restrict__ outb) {
    __shared__ __hip_bfloat16 Ks[2][64][64];
    __shared__ __hip_bfloat16 Vt[2][64][72];

    const int tid = threadIdx.x;
    const int lane = tid & 63;
    const int w = tid >> 6;
    const int bh = blockIdx.x;                   // b*H + h (32), fastest dim
    const int b = bh >> 4, h = bh & 15;
    const int g = lane >> 4;    // 0..3
    const int lc = lane & 15;   // 0..15
    const int lq = w * 16 + lc; // q-row within the 64-row tile

    constexpr float LOG2E = 1.44269504088896f;
    constexpr float SC = 0.125f * LOG2E;                        // qk scale, log2 domain
    const float slope2 = exp2f(-0.5f * (float)(h + 1)) * LOG2E; // alibi slope, log2 domain

    const size_t rowstride = 3 * D_;
    const size_t base = (size_t)b * S_ * rowstride + h * HD_;

    const int srow = tid >> 3;           // 0..31
    const int sc0 = (tid & 7) * 8;
    const int kscol = sc0 ^ ((srow & 7) << 3);   // K source pre-swizzle
    const int vwsz = (tid & 7) << 3;             // Vt write col-swizzle key

    const int qt = 31 - blockIdx.y;              // longest-first dispatch
    const int qg = qt * 64 + lq;                 // global q row

    // Q fragments (B-operand layout: n=q=lc, k contiguous 8g+j)
    bf16x8 aq[2];
#pragma unroll
    for (int kk = 0; kk < 2; ++kk)
        aq[kk] = *reinterpret_cast<const bf16x8*>(
            &qkv[base + (size_t)qg * rowstride + kk * 32 + g * 8]);

    // hoisted alibi per-slot offsets: slope2 * koff (tile-local)
    float ab[16];
#pragma unroll
    for (int ni = 0; ni < 4; ++ni)
#pragma unroll
        for (int r = 0; r < 4; ++r)
            ab[ni * 4 + r] = slope2 * (float)(16 * ni + 4 * g + r);

    f32x4 o[4] = {};

    // ---- prologue: stage DIAG tile (kt=qt) into buf 0 ----
#pragma unroll
    for (int p = 0; p < 2; ++p) {
        int r = p * 32 + srow;
        gload_lds16(&qkv[base + (size_t)(qt * 64 + r) * rowstride + D_ + kscol],
                    &Ks[0][r][sc0]);
        uint4 vv = *reinterpret_cast<const uint4*>(
            &qkv[base + (size_t)(qt * 64 + r) * rowstride + 2 * D_ + sc0]);
        const __hip_bfloat16* ve = reinterpret_cast<const __hip_bfloat16*>(&vv);
#pragma unroll
        for (int j = 0; j < 8; ++j)
            Vt[0][sc0 + j][r ^ vwsz] = ve[j];
    }
    __syncthreads();

    // ================= diag iteration (kt = qt, masked) =================
    float m_run, l_run;
    int cur = 0;
    {
        const bool havepre = (qt > 0);
        uint4 vpre[2];
        if (havepre) {
#pragma unroll
            for (int p = 0; p < 2; ++p) {
                int r = p * 32 + srow;
                gload_lds16(&qkv[base + (size_t)((qt - 1) * 64 + r) * rowstride + D_ + kscol],
                            &Ks[1][r][sc0]);
                vpre[p] = *reinterpret_cast<const uint4*>(
                    &qkv[base + (size_t)((qt - 1) * 64 + r) * rowstride + 2 * D_ + sc0]);
            }
        }

        f32x4 s[4] = {};
#pragma unroll
        for (int ni = 0; ni < 4; ++ni)
#pragma unroll
            for (int kk = 0; kk < 2; ++kk) {
                int row = ni * 16 + lc;
                bf16x8 kf = *reinterpret_cast<const bf16x8*>(
                    &Ks[0][row][(kk * 32 + g * 8) ^ ((row & 7) << 3)]);
                s[ni] = __builtin_amdgcn_mfma_f32_16x16x32_bf16(kf, aq[kk], s[ni], 0, 0, 0);
            }

        float v[16];
#pragma unroll
        for (int ni = 0; ni < 4; ++ni)
#pragma unroll
            for (int r = 0; r < 4; ++r) {
                const int koff = 16 * ni + 4 * g + r;
                float t = fmaf(s[ni][r], SC, ab[ni * 4 + r]);
                if (koff > lq) t = -3e38f;     // causal mask (diag only)
                v[ni * 4 + r] = t;
            }

        float t8[8], t4[4];
#pragma unroll
        for (int i = 0; i < 8; ++i) t8[i] = fmaxf(v[i], v[i + 8]);
#pragma unroll
        for (int i = 0; i < 4; ++i) t4[i] = fmaxf(t8[i], t8[i + 4]);
        float rm = fmaxf(fmaxf(t4[0], t4[1]), fmaxf(t4[2], t4[3]));
        rm = fmaxf(rm, __shfl_xor(rm, 16, 64));
        rm = fmaxf(rm, __shfl_xor(rm, 32, 64));

        // absolute max = rm + b0_diag, with b0_diag = slope2*(qt*64 - qg) = -slope2*lq
        m_run = rm - slope2 * (float)lq;

#pragma unroll
        for (int i = 0; i < 16; ++i) v[i] = exp2f(v[i] - rm);
        float s8[8], s4[4];
#pragma unroll
        for (int i = 0; i < 8; ++i) s8[i] = v[i] + v[i + 8];
#pragma unroll
        for (int i = 0; i < 4; ++i) s4[i] = s8[i] + s8[i + 4];
        float rs = (s4[0] + s4[1]) + (s4[2] + s4[3]);
        rs += __shfl_xor(rs, 16, 64);
        rs += __shfl_xor(rs, 32, 64);
        l_run = rs;

        bf16x4 pb[4];
#pragma unroll
        for (int ni = 0; ni < 4; ++ni)
#pragma unroll
            for (int r = 0; r < 4; ++r)
                pb[ni][r] = f2bf(v[ni * 4 + r]);

#pragma unroll
        for (int oi = 0; oi < 4; ++oi) {
            const int row = oi * 16 + lc;                  // hd
            const int key = ((row >> 3) & 7) << 3;
#pragma unroll
            for (int ni = 0; ni < 4; ++ni) {
                bf16x4 vf = *reinterpret_cast<const bf16x4*>(
                    &Vt[0][row][(ni * 16 + 4 * g) ^ key]);
                MFMA16(o[oi], vf, pb[ni]);
            }
        }

        if (havepre) {
#pragma unroll
            for (int p = 0; p < 2; ++p) {
                int r = p * 32 + srow;
                const __hip_bfloat16* ve = reinterpret_cast<const __hip_bfloat16*>(&vpre[p]);
#pragma unroll
                for (int j = 0; j < 8; ++j)
                    Vt[1][sc0 + j][r ^ vwsz] = ve[j];
            }
        }
        __syncthreads();
        cur = 1;
    }

    // ================= main loop (kt = qt-1 .. 0, mask-free) =================
    for (int kt = qt - 1; kt >= 0; --kt) {
        const bool havepre = (kt > 0);
        uint4 vpre[2];
        if (havepre) {
#pragma unroll
            for (int p = 0; p < 2; ++p) {
                int r = p * 32 + srow;
                gload_lds16(&qkv[base + (size_t)((kt - 1) * 64 + r) * rowstride + D_ + kscol],
                            &Ks[cur ^ 1][r][sc0]);
                vpre[p] = *reinterpret_cast<const uint4*>(
                    &qkv[base + (size_t)((kt - 1) * 64 + r) * rowstride + 2 * D_ + sc0]);
            }
        }

        f32x4 s[4] = {};
#pragma unroll
        for (int ni = 0; ni < 4; ++ni)
#pragma unroll
            for (int kk = 0; kk < 2; ++kk) {
                int row = ni * 16 + lc;
                bf16x8 kf = *reinterpret_cast<const bf16x8*>(
                    &Ks[cur][row][(kk * 32 + g * 8) ^ ((row & 7) << 3)]);
                s[ni] = __builtin_amdgcn_mfma_f32_16x16x32_bf16(kf, aq[kk], s[ni], 0, 0, 0);
            }

        // v (tile-local log2 domain, NO b0, NO mask)
        float v[16];
#pragma unroll
        for (int ni = 0; ni < 4; ++ni)
#pragma unroll
            for (int r = 0; r < 4; ++r)
                v[ni * 4 + r] = fmaf(s[ni][r], SC, ab[ni * 4 + r]);

        float t8[8], t4[4];
#pragma unroll
        for (int i = 0; i < 8; ++i) t8[i] = fmaxf(v[i], v[i + 8]);
#pragma unroll
        for (int i = 0; i < 4; ++i) t4[i] = fmaxf(t8[i], t8[i + 4]);
        float rm = fmaxf(fmaxf(t4[0], t4[1]), fmaxf(t4[2], t4[3]));
        rm = fmaxf(rm, __shfl_xor(rm, 16, 64));
        rm = fmaxf(rm, __shfl_xor(rm, 32, 64));

        const float b0 = slope2 * (float)(kt * 64 - qg);
        float mloc = m_run - b0;                 // running max in tile-local units
        if (__any(rm > mloc)) {                  // rare: max grew (alpha != 1)
            const float mnew = fmaxf(m_run, rm + b0);
            const float alpha = exp2f(m_run - mnew);
#pragma unroll
            for (int oi = 0; oi < 4; ++oi)
#pragma unroll
                for (int r = 0; r < 4; ++r) o[oi][r] *= alpha;
            l_run *= alpha;
            m_run = mnew;
            mloc = m_run - b0;
        }

#pragma unroll
        for (int i = 0; i < 16; ++i) v[i] = exp2f(v[i] - mloc);
        float s8[8], s4[4];
#pragma unroll
        for (int i = 0; i < 8; ++i) s8[i] = v[i] + v[i + 8];
#pragma unroll
        for (int i = 0; i < 4; ++i) s4[i] = s8[i] + s8[i + 4];
        float rs = (s4[0] + s4[1]) + (s4[2] + s4[3]);
        rs += __shfl_xor(rs, 16, 64);
        rs += __shfl_xor(rs, 32, 64);
        l_run += rs;

        bf16x4 pb[4];
#pragma unroll
        for (int ni = 0; ni < 4; ++ni)
#pragma unroll
            for (int r = 0; r < 4; ++r)
                pb[ni][r] = f2bf(v[ni * 4 + r]);

#pragma unroll
        for (int oi = 0; oi < 4; ++oi) {
            const int row = oi * 16 + lc;                  // hd
            const int key = ((row >> 3) & 7) << 3;
#pragma unroll
            for (int ni = 0; ni < 4; ++ni) {
                bf16x4 vf = *reinterpret_cast<const bf16x4*>(
                    &Vt[cur][row][(ni * 16 + 4 * g) ^ key]);
                MFMA16(o[oi], vf, pb[ni]);
            }
        }

        if (havepre) {
#pragma unroll
            for (int p = 0; p < 2; ++p) {
                int r = p * 32 + srow;
                const __hip_bfloat16* ve = reinterpret_cast<const __hip_bfloat16*>(&vpre[p]);
#pragma unroll
                for (int j = 0; j < 8; ++j)
                    Vt[cur ^ 1][sc0 + j][r ^ vwsz] = ve[j];
            }
        }
        __syncthreads();
        cur ^= 1;
    }

    // ---- epilogue: normalize, pack 4 contiguous hd per ushort4 store ----
    const float inv = 1.0f / l_run;
#pragma unroll
    for (int oi = 0; oi < 4; ++oi) {
        union { ushort4 u; short s[4]; } pk;
#pragma unroll
        for (int r = 0; r < 4; ++r) pk.s[r] = f2bf(o[oi][r] * inv);
        *reinterpret_cast<ushort4*>(
            &outb[(size_t)(b * S_ + qg) * D_ + h * HD_ + oi * 16 + 4 * g]) = pk.u;
    }
}

// ---------------------------------------------------------------------------
extern "C" void kernel_launch(void* const* d_in, const int* in_sizes, int n_in,
                              void* d_out, int out_size, void* d_ws, size_t ws_size,
                              hipStream_t stream) {
    const float* x  = (const float*)d_in[0];
    const float* Wq = (const float*)d_in[1];
    const float* bq = (const float*)d_in[2];
    const float* Wk = (const float*)d_in[3];
    const float* bk = (const float*)d_in[4];
    const float* Wv = (const float*)d_in[5];
    const float* bv = (const float*)d_in[6];
    const float* Wo = (const float*)d_in[7];
    const float* bo = (const float*)d_in[8];

    char* ws = (char*)d_ws;
    __hip_bfloat16* xb    = (__hip_bfloat16*)(ws);                       // 8 MB
    __hip_bfloat16* Wqkvt = (__hip_bfloat16*)(ws + (size_t)(8u  << 20)); // 6 MB
    __hip_bfloat16* Wot   = (__hip_bfloat16*)(ws + (size_t)(14u << 20)); // 2 MB
    __hip_bfloat16* qkv   = (__hip_bfloat16*)(ws + (size_t)(16u << 20)); // 24 MB
    __hip_bfloat16* attnb = (__hip_bfloat16*)(ws + (size_t)(40u << 20)); // 8 MB
    float* biasf          = (float*)(ws + (size_t)(48u << 20));          // 12 KB

    const int nX = B_ * S_ * D_;   // 4194304

    f32_to_bf16_vec<<<4096, 256, 0, stream>>>(x, xb, nX);
    transpose4_f32_to_bf16<<<dim3(32, 32, 4), 256, 0, stream>>>(
        Wq, Wk, Wv, Wo, Wqkvt, Wqkvt + D_ * D_, Wqkvt + 2 * D_ * D_, Wot);
    concat_bias<<<12, 256, 0, stream>>>(bq, bk, bv, biasf);

    // QKV projection: [4096 x 1024] @ [1024 x 3072] -> qkv (bf16)
    gemm_bt_kernel<false, 128><<<dim3(32, 24), 256, 0, stream>>>(
        xb, Wqkvt, biasf, qkv, B_ * S_, 3 * D_, D_);

    // Attention: grid (bh fastest, qt longest-first)
    attn_kernel<<<dim3(B_ * H_, S_ / 64), 256, 0, stream>>>(qkv, attnb);

    // Output projection: [4096 x 1024] @ [1024 x 1024] -> d_out (fp32), BN=64
    gemm_bt_kernel<true, 64><<<dim3(32, 16), 256, 0, stream>>>(
        attnb, Wot, bo, (float*)d_out, B_ * S_, D_, D_);
}